// Round 1
// 449.030 us; speedup vs baseline: 1.0212x; 1.0212x over previous
//
#include <hip/hip_runtime.h>

// cumprod along dim=1 of (B=32, L=4096, C=512) fp32.
// Single-pass block-chunked scan, restructured for minimal barriers:
//  - per 512-l chunk: 8 float4/thread in regs -> local chain ->
//    in-wave shuffle scan over 8 w-slots (no barrier) ->
//    8 wave-totals through LDS with ONE raw s_barrier (no vmcnt drain) ->
//    apply carry -> nontemporal store.
//  - next chunk's loads are prefetched into registers before the scan;
//    they survive the barrier because we never drain vmcnt.
// Traffic = 268 MB read + 268 MB write, ~85 us floor @6.3 TB/s.

typedef float f4 __attribute__((ext_vector_type(4)));

constexpr int L  = 4096;  // scan length
constexpr int C  = 512;   // channels
constexpr int C4 = C / 4; // float4 groups per row = 128
constexpr int CG = 8;     // float4 groups per block (32 channels)
constexpr int W  = 64;    // l-segments per chunk (threads along l)
constexpr int KE = 8;     // l elements per thread per chunk
constexpr int CL = W * KE;        // 512 l per chunk
constexpr int NCHUNK = L / CL;    // 8
constexpr int NWAVE = CG * W / 64; // 8 waves per block
constexpr int WPW = 64 / CG;      // w-slots per wave = 8

__device__ __forceinline__ f4 shflup(f4 v, int lanes) {
    f4 r;
#pragma unroll
    for (int j = 0; j < 4; ++j) r[j] = __shfl_up(v[j], lanes, 64);
    return r;
}

__global__ __launch_bounds__(CG * W, 4)  // 512 threads, <=128 VGPR, 2 blocks/CU
void cumprod_kernel(const f4* __restrict__ x, f4* __restrict__ out) {
    // double-buffered wave totals: no trailing barrier needed
    __shared__ f4 s[2][NWAVE][CG + 1];

    const int tid  = threadIdx.x;
    const int c4   = tid & (CG - 1);   // fast index: channel -> coalescing
    const int w    = tid >> 3;         // l-segment within chunk, 0..63
    const int lane = tid & 63;
    const int wi   = lane >> 3;        // w-slot within wave, 0..7
    const int ww   = tid >> 6;         // wave id, 0..7
    const int c4g  = blockIdx.x * CG + c4;
    const int b    = blockIdx.y;
    const int base = (b * L) * C4 + c4g;  // fits int32 (max ~16.8M)

    f4 carry = {1.f, 1.f, 1.f, 1.f};

    // ---- prefetch chunk 0 ----
    f4 p[KE];
    {
        const int lb = base + (w * KE) * C4;
#pragma unroll
        for (int i = 0; i < KE; ++i)
            p[i] = __builtin_nontemporal_load(&x[lb + i * C4]);
    }

    for (int chunk = 0; chunk < NCHUNK; ++chunk) {
        // consume prefetch
        f4 v[KE];
#pragma unroll
        for (int i = 0; i < KE; ++i) v[i] = p[i];

        // issue next chunk's loads NOW -> in flight across scan+store+barrier
        if (chunk + 1 < NCHUNK) {
            const int lb = base + ((chunk + 1) * CL + w * KE) * C4;
#pragma unroll
            for (int i = 0; i < KE; ++i)
                p[i] = __builtin_nontemporal_load(&x[lb + i * C4]);
        }

        // ---- local inclusive products (register chain) ----
#pragma unroll
        for (int i = 1; i < KE; ++i) v[i] = v[i] * v[i - 1];

        // ---- in-wave inclusive scan of segment products over 8 w-slots ----
        f4 seg = v[KE - 1];
#pragma unroll
        for (int d = 1; d < WPW; d <<= 1) {
            f4 t = shflup(seg, d * CG);   // value from w-slot (wi - d)
            if (wi >= d) seg = seg * t;
        }

        // exclusive-within-wave prefix (segments ww*8 .. ww*8+wi-1)
        f4 exw = shflup(seg, CG);

        // wave totals -> LDS (lanes with wi==7 hold them)
        if (wi == WPW - 1) s[chunk & 1][ww][c4] = seg;

        // barrier WITHOUT vmcnt drain: LDS-visibility only
        asm volatile("s_waitcnt lgkmcnt(0)" ::: "memory");
        __builtin_amdgcn_s_barrier();

        // prefix over lower waves' totals + chunk total (loop bound uniform per wave)
        f4 wpre = {1.f, 1.f, 1.f, 1.f};
        f4 tot  = {1.f, 1.f, 1.f, 1.f};
#pragma unroll
        for (int j = 0; j < NWAVE; ++j) {
            f4 sj = s[chunk & 1][j][c4];
            if (j < ww) wpre = wpre * sj;
            tot = tot * sj;
        }

        f4 pref = carry * wpre;
        if (wi > 0) pref = pref * exw;

        // ---- apply prefix and store (nontemporal: never re-read) ----
        const int lb = base + (chunk * CL + w * KE) * C4;
#pragma unroll
        for (int i = 0; i < KE; ++i)
            __builtin_nontemporal_store(pref * v[i], &out[lb + i * C4]);

        carry = carry * tot;
        // no trailing barrier: next chunk writes the other s[] buffer
    }
}

extern "C" void kernel_launch(void* const* d_in, const int* in_sizes, int n_in,
                              void* d_out, int out_size, void* d_ws, size_t ws_size,
                              hipStream_t stream) {
    const f4* x = (const f4*)d_in[0];
    f4* out = (f4*)d_out;

    const int B = in_sizes[0] / (L * C);  // = 32

    dim3 grid(C4 / CG, B);   // (16, 32) = 512 blocks = 2/CU exactly
    dim3 block(CG * W);      // 512 threads = 8 waves
    cumprod_kernel<<<grid, block, 0, stream>>>(x, out);
}